// Round 3
// baseline (120.844 us; speedup 1.0000x reference)
//
#include <hip/hip_runtime.h>
#include <hip/hip_bf16.h>

typedef __attribute__((ext_vector_type(8))) short bf16x8;
typedef __attribute__((ext_vector_type(4))) float f32x4;

#define B_ROWS 4096
#define H_DIM  1024
#define TEMP_INV 20.0f
#define BM 256
#define BK 64
#define NT (H_DIM / BK)   // 16 K-tiles

__device__ __forceinline__ void gload_lds16(const void* g, void* l) {
  __builtin_amdgcn_global_load_lds(
      (const __attribute__((address_space(1))) void*)g,
      (__attribute__((address_space(3))) void*)l, 16, 0, 0);
}

// Kernel 1: row-normalize (f32, cosine_similarity eps) and cast to bf16.
// Blocks 0..15 also zero the rowsum accumulator.
__global__ __launch_bounds__(256) void normalize_kernel(
    const float* __restrict__ cls, const float* __restrict__ hid,
    __hip_bfloat16* __restrict__ Abf, __hip_bfloat16* __restrict__ Bbf,
    float* __restrict__ rowsum)
{
  int bid = blockIdx.x, tid = threadIdx.x;
  if (bid < 16) rowsum[bid * 256 + tid] = 0.0f;
  int row = bid & (B_ROWS - 1);
  const float* src = (bid < B_ROWS) ? cls : hid;
  __hip_bfloat16* dst = (bid < B_ROWS) ? Abf : Bbf;

  float4 v = reinterpret_cast<const float4*>(src + (size_t)row * H_DIM)[tid];
  float ss = v.x * v.x + v.y * v.y + v.z * v.z + v.w * v.w;
  #pragma unroll
  for (int off = 1; off < 64; off <<= 1) ss += __shfl_xor(ss, off, 64);
  __shared__ float wsum[4];
  if ((tid & 63) == 0) wsum[tid >> 6] = ss;
  __syncthreads();
  float total = wsum[0] + wsum[1] + wsum[2] + wsum[3];
  float scale = 1.0f / fmaxf(sqrtf(total), 1e-8f);

  union { ushort4 u; __hip_bfloat16 h[4]; } o;
  o.h[0] = __float2bfloat16(v.x * scale);
  o.h[1] = __float2bfloat16(v.y * scale);
  o.h[2] = __float2bfloat16(v.z * scale);
  o.h[3] = __float2bfloat16(v.w * scale);
  reinterpret_cast<ushort4*>(dst + (size_t)row * H_DIM)[tid] = o.u;
}

// Kernel 2: 256x256-tile NT-GEMM, 8 waves (2Mx4N), BK=64, double-buffered
// 128 KiB LDS, template-exact 4-phase schedule: {reads; stage; s_barrier;
// lgkmcnt(0)+sched_barrier; setprio(1); 16 MFMA; setprio(0); s_barrier}.
// Read distribution {8,4,8,4}: B[0..1] frags read-ahead in prev tile's P4
// (bfr[0..1] dead after MFMA(4,0); buf^1 B01 resident after vmcnt(2)+bar).
// Counted vmcnt(2) once per K-tile. XOR-swizzled LDS both-sides.

#define LDS_RD_A(BUF, MB)                                                     \
  { _Pragma("unroll") for (int mi = 0; mi < 4; mi++) {                        \
      _Pragma("unroll") for (int ks = 0; ks < 2; ks++) {                      \
        af[mi][ks] = *(const bf16x8*)(&As[BUF][(rA2 ^ (ks << 6)) + ((MB) + mi) * 2048]); } } }

#define LDS_RD_B(BUF, NB)                                                     \
  { _Pragma("unroll") for (int ni = 0; ni < 2; ni++) {                        \
      _Pragma("unroll") for (int ks = 0; ks < 2; ks++) {                      \
        bfr[(NB) + ni][ks] = *(const bf16x8*)(&Bs[BUF][(rB2 ^ (ks << 6)) + ((NB) + ni) * 2048]); } } }

#define MFMA16(MB, NB)                                                        \
  { __builtin_amdgcn_s_setprio(1);                                            \
    _Pragma("unroll") for (int mi = 0; mi < 4; mi++) {                        \
      _Pragma("unroll") for (int ni = 0; ni < 2; ni++) {                      \
        _Pragma("unroll") for (int ks = 0; ks < 2; ks++) {                    \
          acc[(MB) + mi][(NB) + ni] = __builtin_amdgcn_mfma_f32_16x16x32_bf16(\
              af[mi][ks], bfr[(NB) + ni][ks], acc[(MB) + mi][(NB) + ni], 0, 0, 0); } } } \
    __builtin_amdgcn_s_setprio(0); }

#define BARB() __builtin_amdgcn_s_barrier()
#define WAITK()                                                               \
  { asm volatile("s_waitcnt lgkmcnt(0)" ::: "memory");                        \
    __builtin_amdgcn_sched_barrier(0); }

#define STAGE_A(BUF, TT, C)                                                   \
  gload_lds16(Abase + (size_t)(row0 + (C) * 64 + srow) * 2048 + (TT) * 128 + scolb, \
              &As[BUF][(C) * 8192 + tid * 16])
#define STAGE_B(BUF, TT, C)                                                   \
  gload_lds16(Bbase + (size_t)(col0 + (C) * 64 + srow) * 2048 + (TT) * 128 + scolb, \
              &Bs[BUF][(C) * 8192 + tid * 16])

#define KTILE(BUF, T_)                                                        \
  { const int Tn = (T_) + 1;                                                  \
    /* P1: A[0..3]; stage next A c2,c3 */                                     \
    LDS_RD_A(BUF, 0);                                                         \
    if (Tn < NT) { STAGE_A(BUF ^ 1, Tn, 2); STAGE_A(BUF ^ 1, Tn, 3); }        \
    BARB(); WAITK(); MFMA16(0, 0); BARB();                                    \
    /* P2: B[2..3]; stage next B c0,c1 */                                     \
    LDS_RD_B(BUF, 2);                                                         \
    if (Tn < NT) { STAGE_B(BUF ^ 1, Tn, 0); STAGE_B(BUF ^ 1, Tn, 1); }        \
    BARB(); WAITK(); MFMA16(0, 2); BARB();                                    \
    /* P3: A[4..7]; stage next B c2,c3 */                                     \
    LDS_RD_A(BUF, 4);                                                         \
    if (Tn < NT) { STAGE_B(BUF ^ 1, Tn, 2); STAGE_B(BUF ^ 1, Tn, 3); }        \
    BARB(); WAITK(); MFMA16(4, 0); BARB();                                    \
    /* P4: stage T+2 A c0,c1; counted vmcnt; read-ahead next B[0..1] */       \
    if ((T_) + 2 < NT) {                                                      \
      STAGE_A(BUF, (T_) + 2, 0); STAGE_A(BUF, (T_) + 2, 1);                   \
      asm volatile("s_waitcnt vmcnt(2)" ::: "memory");                        \
    } else if (Tn < NT) {                                                     \
      asm volatile("s_waitcnt vmcnt(0)" ::: "memory");                        \
    }                                                                         \
    BARB();                                                                   \
    if (Tn < NT) { LDS_RD_B(BUF ^ 1, 0); }                                    \
    MFMA16(4, 2); BARB(); }

__global__ __launch_bounds__(512, 2) void gemm_kernel(
    const __hip_bfloat16* __restrict__ A, const __hip_bfloat16* __restrict__ Bm,
    float* __restrict__ rowsum, float* __restrict__ diag)
{
  __shared__ __align__(16) char As[2][32768];   // [2 dbuf][256 rows][64 cols] bf16
  __shared__ __align__(16) char Bs[2][32768];

  const int tid  = threadIdx.x;
  const int lane = tid & 63;
  const int w    = tid >> 6;            // 0..7
  const int wm   = w >> 2, wn = w & 3;  // 2 x 4 wave grid
  const int bm = blockIdx.y, bn = blockIdx.x;
  const long row0 = (long)bm * BM, col0 = (long)bn * BM;
  const char* Abase = (const char*)A;
  const char* Bbase = (const char*)Bm;

  // Stage addressing: linear LDS dest at chunk*8192 + tid*16;
  // swizzle s(L) = L ^ ((row&7)<<4) -> fetch global from logical L = s(p).
  const int srow  = tid >> 3;                                   // 0..63 in chunk
  const int scolb = ((tid & 7) ^ ((tid >> 3) & 7)) << 4;        // swizzled col byte

  // Read addressing (swizzled).
  const int dsw = (lane & 7) << 4;
  const int rA2 = (((wm * 128 + (lane & 15)) * 128) + ((lane >> 4) * 16)) ^ dsw;
  const int rB2 = (((wn * 64  + (lane & 15)) * 128) + ((lane >> 4) * 16)) ^ dsw;

  f32x4 acc[8][4] = {};
  bf16x8 af[4][2], bfr[4][2];

  // Prologue: stage tile 0 fully + tile 1's A c0,c1; counted wait; pre-read
  // tile 0's B[0..1] fragments (the "P4-prev" read for the first P1).
  #pragma unroll
  for (int c = 0; c < 4; c++) STAGE_A(0, 0, c);
  #pragma unroll
  for (int c = 0; c < 4; c++) STAGE_B(0, 0, c);
  STAGE_A(1, 1, 0); STAGE_A(1, 1, 1);
  asm volatile("s_waitcnt vmcnt(2)" ::: "memory");
  BARB();
  LDS_RD_B(0, 0);

  #pragma unroll 1
  for (int T = 0; T < NT; T += 2) {
    KTILE(0, T);
    KTILE(1, T + 1);
  }

  // Epilogue: sim = acc*20; diag capture; p = exp(sim); per-row reduce.
  const bool isdiag = (bm == bn);
  const int g = lane >> 4;            // C/D: row=(lane>>4)*4+r, col=lane&15
  #pragma unroll
  for (int m = 0; m < 8; m++) {
    const int rowb = (int)row0 + wm * 128 + m * 16 + g * 4;
    float p[4] = {0.f, 0.f, 0.f, 0.f};
    #pragma unroll
    for (int n = 0; n < 4; n++) {
      const int colb = (int)col0 + wn * 64 + n * 16 + (lane & 15);
      #pragma unroll
      for (int r = 0; r < 4; r++) {
        float sim = acc[m][n][r] * TEMP_INV;
        if (isdiag && (rowb + r == colb)) diag[rowb + r] = sim;
        p[r] += __expf(sim);
      }
    }
    #pragma unroll
    for (int r = 0; r < 4; r++) {
      float s = p[r];
      s += __shfl_xor(s, 1, 64);
      s += __shfl_xor(s, 2, 64);
      s += __shfl_xor(s, 4, 64);
      s += __shfl_xor(s, 8, 64);
      if ((lane & 15) == 0) atomicAdd(&rowsum[rowb + r], s);
    }
  }
}

// Kernel 3: out = mean(log(rowsum) - diag)
__global__ __launch_bounds__(1024) void finalize_kernel(
    const float* __restrict__ rowsum, const float* __restrict__ diag,
    float* __restrict__ out)
{
  int tid = threadIdx.x;
  float acc = 0.f;
  for (int i = tid; i < B_ROWS; i += 1024)
    acc += logf(rowsum[i]) - diag[i];
  #pragma unroll
  for (int off = 1; off < 64; off <<= 1) acc += __shfl_xor(acc, off, 64);
  __shared__ float wsum[16];
  if ((tid & 63) == 0) wsum[tid >> 6] = acc;
  __syncthreads();
  if (tid == 0) {
    float t = 0.f;
    #pragma unroll
    for (int i = 0; i < 16; i++) t += wsum[i];
    out[0] = t * (1.0f / B_ROWS);
  }
}

extern "C" void kernel_launch(void* const* d_in, const int* in_sizes, int n_in,
                              void* d_out, int out_size, void* d_ws, size_t ws_size,
                              hipStream_t stream)
{
  const float* cls = (const float*)d_in[0];
  const float* hid = (const float*)d_in[1];
  float* out = (float*)d_out;
  char* ws = (char*)d_ws;

  __hip_bfloat16* Abf = (__hip_bfloat16*)ws;                                // 8 MB
  __hip_bfloat16* Bbf = (__hip_bfloat16*)(ws + (size_t)B_ROWS * H_DIM * 2); // 8 MB
  float* rowsum = (float*)(ws + (size_t)B_ROWS * H_DIM * 4);                // 16 KB
  float* diag   = rowsum + B_ROWS;                                          // 16 KB

  hipLaunchKernelGGL(normalize_kernel, dim3(2 * B_ROWS), dim3(256), 0, stream,
                     cls, hid, Abf, Bbf, rowsum);
  hipLaunchKernelGGL(gemm_kernel, dim3(B_ROWS / BM, B_ROWS / BM), dim3(512), 0, stream,
                     Abf, Bbf, rowsum, diag);
  hipLaunchKernelGGL(finalize_kernel, dim3(1), dim3(1024), 0, stream,
                     rowsum, diag, out);
}

// Round 4
// 117.925 us; speedup vs baseline: 1.0247x; 1.0247x over previous
//
#include <hip/hip_runtime.h>
#include <hip/hip_bf16.h>

typedef __attribute__((ext_vector_type(8))) short bf16x8;
typedef __attribute__((ext_vector_type(4))) float f32x4;

#define B_ROWS 4096
#define H_DIM  1024
#define TEMP_INV 20.0f
#define BM 256
#define BK 64
#define NT (H_DIM / BK)   // 16 K-tiles
#define NBN (B_ROWS / BM) // 16 column blocks

__device__ __forceinline__ void gload_lds16(const void* g, void* l) {
  __builtin_amdgcn_global_load_lds(
      (const __attribute__((address_space(1))) void*)g,
      (__attribute__((address_space(3))) void*)l, 16, 0, 0);
}

// Kernel 1: row-normalize (f32, cosine_similarity eps) and cast to bf16.
// One row per wave: 64 lanes x 4 float4 = 1024 floats. No LDS, no barrier.
__global__ __launch_bounds__(256) void normalize_kernel(
    const float* __restrict__ cls, const float* __restrict__ hid,
    __hip_bfloat16* __restrict__ Abf, __hip_bfloat16* __restrict__ Bbf)
{
  const int w = threadIdx.x >> 6, lane = threadIdx.x & 63;
  const int r = blockIdx.x * 4 + w;                  // 0..8191
  const int rr = r & (B_ROWS - 1);
  const float* src = ((r < B_ROWS) ? cls : hid) + (size_t)rr * H_DIM;
  __hip_bfloat16* dst = ((r < B_ROWS) ? Abf : Bbf) + (size_t)rr * H_DIM;

  float4 v[4];
  float ss = 0.f;
  #pragma unroll
  for (int j = 0; j < 4; j++) {
    v[j] = reinterpret_cast<const float4*>(src)[j * 64 + lane];
    ss += v[j].x * v[j].x + v[j].y * v[j].y + v[j].z * v[j].z + v[j].w * v[j].w;
  }
  #pragma unroll
  for (int off = 1; off < 64; off <<= 1) ss += __shfl_xor(ss, off, 64);
  const float scale = 1.0f / fmaxf(sqrtf(ss), 1e-8f);

  #pragma unroll
  for (int j = 0; j < 4; j++) {
    union { ushort4 u; __hip_bfloat16 h[4]; } o;
    o.h[0] = __float2bfloat16(v[j].x * scale);
    o.h[1] = __float2bfloat16(v[j].y * scale);
    o.h[2] = __float2bfloat16(v[j].z * scale);
    o.h[3] = __float2bfloat16(v[j].w * scale);
    reinterpret_cast<ushort4*>(dst)[j * 64 + lane] = o.u;
  }
}

// Kernel 2: 256x256-tile NT-GEMM, 8 waves (2Mx4N), BK=64, dbuf 128 KiB LDS,
// 4-phase schedule {reads; stage; s_barrier; lgkmcnt(0)+sched_barrier;
// setprio(1); 16 MFMA; setprio(0); s_barrier}, counted vmcnt(2), XOR-swizzle.
// Epilogue: exp + 16-lane shuffle reduce -> LDS combine across wn waves ->
// ONE coalesced non-atomic store of 256 partials per block (no atomics).

#define LDS_RD_A(BUF, MB)                                                     \
  { _Pragma("unroll") for (int mi = 0; mi < 4; mi++) {                        \
      _Pragma("unroll") for (int ks = 0; ks < 2; ks++) {                      \
        af[mi][ks] = *(const bf16x8*)(&As[BUF][(rA2 ^ (ks << 6)) + ((MB) + mi) * 2048]); } } }

#define LDS_RD_B(BUF, NB)                                                     \
  { _Pragma("unroll") for (int ni = 0; ni < 2; ni++) {                        \
      _Pragma("unroll") for (int ks = 0; ks < 2; ks++) {                      \
        bfr[(NB) + ni][ks] = *(const bf16x8*)(&Bs[BUF][(rB2 ^ (ks << 6)) + ((NB) + ni) * 2048]); } } }

#define MFMA16(MB, NB)                                                        \
  { __builtin_amdgcn_s_setprio(1);                                            \
    _Pragma("unroll") for (int mi = 0; mi < 4; mi++) {                        \
      _Pragma("unroll") for (int ni = 0; ni < 2; ni++) {                      \
        _Pragma("unroll") for (int ks = 0; ks < 2; ks++) {                    \
          acc[(MB) + mi][(NB) + ni] = __builtin_amdgcn_mfma_f32_16x16x32_bf16(\
              af[mi][ks], bfr[(NB) + ni][ks], acc[(MB) + mi][(NB) + ni], 0, 0, 0); } } } \
    __builtin_amdgcn_s_setprio(0); }

#define BARB() __builtin_amdgcn_s_barrier()
#define WAITK()                                                               \
  { asm volatile("s_waitcnt lgkmcnt(0)" ::: "memory");                        \
    __builtin_amdgcn_sched_barrier(0); }

#define STAGE_A(BUF, TT, C)                                                   \
  gload_lds16(Abase + (size_t)(row0 + (C) * 64 + srow) * 2048 + (TT) * 128 + scolb, \
              &As[BUF][(C) * 8192 + tid * 16])
#define STAGE_B(BUF, TT, C)                                                   \
  gload_lds16(Bbase + (size_t)(col0 + (C) * 64 + srow) * 2048 + (TT) * 128 + scolb, \
              &Bs[BUF][(C) * 8192 + tid * 16])

#define KTILE(BUF, T_)                                                        \
  { const int Tn = (T_) + 1;                                                  \
    LDS_RD_A(BUF, 0);                                                         \
    if (Tn < NT) { STAGE_A(BUF ^ 1, Tn, 2); STAGE_A(BUF ^ 1, Tn, 3); }        \
    BARB(); WAITK(); MFMA16(0, 0); BARB();                                    \
    LDS_RD_B(BUF, 2);                                                         \
    if (Tn < NT) { STAGE_B(BUF ^ 1, Tn, 0); STAGE_B(BUF ^ 1, Tn, 1); }        \
    BARB(); WAITK(); MFMA16(0, 2); BARB();                                    \
    LDS_RD_A(BUF, 4);                                                         \
    if (Tn < NT) { STAGE_B(BUF ^ 1, Tn, 2); STAGE_B(BUF ^ 1, Tn, 3); }        \
    BARB(); WAITK(); MFMA16(4, 0); BARB();                                    \
    if ((T_) + 2 < NT) {                                                      \
      STAGE_A(BUF, (T_) + 2, 0); STAGE_A(BUF, (T_) + 2, 1);                   \
      asm volatile("s_waitcnt vmcnt(2)" ::: "memory");                        \
    } else if (Tn < NT) {                                                     \
      asm volatile("s_waitcnt vmcnt(0)" ::: "memory");                        \
    }                                                                         \
    BARB();                                                                   \
    if (Tn < NT) { LDS_RD_B(BUF ^ 1, 0); }                                    \
    MFMA16(4, 2); BARB(); }

__global__ __launch_bounds__(512, 2) void gemm_kernel(
    const __hip_bfloat16* __restrict__ A, const __hip_bfloat16* __restrict__ Bm,
    float* __restrict__ pp, float* __restrict__ diag)
{
  __shared__ __align__(16) char As[2][32768];   // [2 dbuf][256 rows][64 cols] bf16
  __shared__ __align__(16) char Bs[2][32768];

  const int tid  = threadIdx.x;
  const int lane = tid & 63;
  const int w    = tid >> 6;            // 0..7
  const int wm   = w >> 2, wn = w & 3;  // 2 x 4 wave grid
  const int bm = blockIdx.y, bn = blockIdx.x;
  const long row0 = (long)bm * BM, col0 = (long)bn * BM;
  const char* Abase = (const char*)A;
  const char* Bbase = (const char*)Bm;

  const int srow  = tid >> 3;                                   // 0..63 in chunk
  const int scolb = ((tid & 7) ^ ((tid >> 3) & 7)) << 4;        // swizzled col byte

  const int dsw = (lane & 7) << 4;
  const int rA2 = (((wm * 128 + (lane & 15)) * 128) + ((lane >> 4) * 16)) ^ dsw;
  const int rB2 = (((wn * 64  + (lane & 15)) * 128) + ((lane >> 4) * 16)) ^ dsw;

  f32x4 acc[8][4] = {};
  bf16x8 af[4][2], bfr[4][2];

  // Prologue: stage tile 0 fully + tile 1's A c0,c1; counted wait; pre-read
  // tile 0's B[0..1] fragments.
  #pragma unroll
  for (int c = 0; c < 4; c++) STAGE_A(0, 0, c);
  #pragma unroll
  for (int c = 0; c < 4; c++) STAGE_B(0, 0, c);
  STAGE_A(1, 1, 0); STAGE_A(1, 1, 1);
  asm volatile("s_waitcnt vmcnt(2)" ::: "memory");
  BARB();
  LDS_RD_B(0, 0);

  #pragma unroll 1
  for (int T = 0; T < NT; T += 2) {
    KTILE(0, T);
    KTILE(1, T + 1);
  }

  // ---- Epilogue (no atomics) ----
  const bool isdiag = (bm == bn);
  const int g = lane >> 4;            // C/D: row=(lane>>4)*4+r, col=lane&15
  __syncthreads();                    // safe LDS reuse point
  float* lds_p = (float*)&As[0][0];   // [4 wn][256 rows] = 4 KB

  #pragma unroll
  for (int m = 0; m < 8; m++) {
    const int rowb = (int)row0 + wm * 128 + m * 16 + g * 4;
    float p[4] = {0.f, 0.f, 0.f, 0.f};
    #pragma unroll
    for (int n = 0; n < 4; n++) {
      const int colb = (int)col0 + wn * 64 + n * 16 + (lane & 15);
      #pragma unroll
      for (int r = 0; r < 4; r++) {
        float sim = acc[m][n][r] * TEMP_INV;
        if (isdiag && (rowb + r == colb)) diag[rowb + r] = sim;
        p[r] += __expf(sim);
      }
    }
    #pragma unroll
    for (int r = 0; r < 4; r++) {
      float s = p[r];
      s += __shfl_xor(s, 1, 64);
      s += __shfl_xor(s, 2, 64);
      s += __shfl_xor(s, 4, 64);
      s += __shfl_xor(s, 8, 64);
      if ((lane & 15) == 0)
        lds_p[wn * 256 + wm * 128 + m * 16 + g * 4 + r] = s;
    }
  }
  __syncthreads();
  if (tid < 256) {
    float s = lds_p[tid] + lds_p[256 + tid] + lds_p[512 + tid] + lds_p[768 + tid];
    pp[(size_t)bn * B_ROWS + row0 + tid] = s;   // coalesced, non-atomic
  }
}

// Kernel 3: out = mean(log(sum_bn pp[bn][i]) - diag[i])
__global__ __launch_bounds__(1024) void finalize_kernel(
    const float* __restrict__ pp, const float* __restrict__ diag,
    float* __restrict__ out)
{
  int tid = threadIdx.x;
  float acc = 0.f;
  for (int i = tid; i < B_ROWS; i += 1024) {
    float s = 0.f;
    #pragma unroll
    for (int j = 0; j < NBN; j++) s += pp[(size_t)j * B_ROWS + i];
    acc += logf(s) - diag[i];
  }
  #pragma unroll
  for (int off = 1; off < 64; off <<= 1) acc += __shfl_xor(acc, off, 64);
  __shared__ float wsum[16];
  if ((tid & 63) == 0) wsum[tid >> 6] = acc;
  __syncthreads();
  if (tid == 0) {
    float t = 0.f;
    #pragma unroll
    for (int i = 0; i < 16; i++) t += wsum[i];
    out[0] = t * (1.0f / B_ROWS);
  }
}

extern "C" void kernel_launch(void* const* d_in, const int* in_sizes, int n_in,
                              void* d_out, int out_size, void* d_ws, size_t ws_size,
                              hipStream_t stream)
{
  const float* cls = (const float*)d_in[0];
  const float* hid = (const float*)d_in[1];
  float* out = (float*)d_out;
  char* ws = (char*)d_ws;

  __hip_bfloat16* Abf = (__hip_bfloat16*)ws;                                // 8 MB
  __hip_bfloat16* Bbf = (__hip_bfloat16*)(ws + (size_t)B_ROWS * H_DIM * 2); // 8 MB
  float* pp   = (float*)(ws + (size_t)B_ROWS * H_DIM * 4);                  // 256 KB
  float* diag = pp + (size_t)NBN * B_ROWS;                                  // 16 KB

  hipLaunchKernelGGL(normalize_kernel, dim3(2 * B_ROWS / 4), dim3(256), 0, stream,
                     cls, hid, Abf, Bbf);
  hipLaunchKernelGGL(gemm_kernel, dim3(B_ROWS / BM, B_ROWS / BM), dim3(512), 0, stream,
                     Abf, Bbf, pp, diag);
  hipLaunchKernelGGL(finalize_kernel, dim3(1), dim3(1024), 0, stream,
                     pp, diag, out);
}

// Round 5
// 116.242 us; speedup vs baseline: 1.0396x; 1.0145x over previous
//
#include <hip/hip_runtime.h>
#include <hip/hip_bf16.h>

typedef __attribute__((ext_vector_type(8))) short bf16x8;
typedef __attribute__((ext_vector_type(4))) float f32x4;

#define B_ROWS 4096
#define H_DIM  1024
#define TEMP_INV 20.0f
#define BM 256
#define BK 64
#define NT (H_DIM / BK)   // 16 K-tiles
#define NBN (B_ROWS / BM) // 16 column blocks

__device__ __forceinline__ void gload_lds16(const void* g, void* l) {
  __builtin_amdgcn_global_load_lds(
      (const __attribute__((address_space(1))) void*)g,
      (__attribute__((address_space(3))) void*)l, 16, 0, 0);
}

// Kernel 1: row-normalize (f32, cosine_similarity eps) and cast to bf16.
// One row per wave: 64 lanes x 4 float4 = 1024 floats. No LDS, no barrier.
__global__ __launch_bounds__(256) void normalize_kernel(
    const float* __restrict__ cls, const float* __restrict__ hid,
    __hip_bfloat16* __restrict__ Abf, __hip_bfloat16* __restrict__ Bbf)
{
  const int w = threadIdx.x >> 6, lane = threadIdx.x & 63;
  const int r = blockIdx.x * 4 + w;                  // 0..8191
  const int rr = r & (B_ROWS - 1);
  const float* src = ((r < B_ROWS) ? cls : hid) + (size_t)rr * H_DIM;
  __hip_bfloat16* dst = ((r < B_ROWS) ? Abf : Bbf) + (size_t)rr * H_DIM;

  float4 v[4];
  float ss = 0.f;
  #pragma unroll
  for (int j = 0; j < 4; j++) {
    v[j] = reinterpret_cast<const float4*>(src)[j * 64 + lane];
    ss += v[j].x * v[j].x + v[j].y * v[j].y + v[j].z * v[j].z + v[j].w * v[j].w;
  }
  #pragma unroll
  for (int off = 1; off < 64; off <<= 1) ss += __shfl_xor(ss, off, 64);
  const float scale = 1.0f / fmaxf(sqrtf(ss), 1e-8f);

  #pragma unroll
  for (int j = 0; j < 4; j++) {
    union { ushort4 u; __hip_bfloat16 h[4]; } o;
    o.h[0] = __float2bfloat16(v[j].x * scale);
    o.h[1] = __float2bfloat16(v[j].y * scale);
    o.h[2] = __float2bfloat16(v[j].z * scale);
    o.h[3] = __float2bfloat16(v[j].w * scale);
    reinterpret_cast<ushort4*>(dst)[j * 64 + lane] = o.u;
  }
}

// Kernel 2: 256x256-tile NT-GEMM, 8 waves (2Mx4N), BK=64, dbuf 128 KiB LDS.
// 4-phase schedule; staging re-timed so each P4 vmcnt(6) retires exactly the
// next tile's 8 loads with >=3 phases of latency cover:
//   P1: rd A[0..3](chunks 0,2) ; stage B23(T+1)->buf^1
//   P2: rd B[2..3](all chunks) ; stage A02(T+2)->buf
//   P3: rd A[4..7](chunks 1,3) ; stage B01(T+2)->buf
//   P4: stage A13(T+2)->buf ; vmcnt(6) ; bar ; read-ahead B[0..1] of buf^1
// Chunk order matches read order, so stages into buf land after their last
// reader's barrier. XCD-swizzled block id (bijective, 256%8==0).

#define LDS_RD_A(BUF, MB)                                                     \
  { _Pragma("unroll") for (int mi = 0; mi < 4; mi++) {                        \
      _Pragma("unroll") for (int ks = 0; ks < 2; ks++) {                      \
        af[mi][ks] = *(const bf16x8*)(&As[BUF][(rA2 ^ (ks << 6)) + ((MB) + mi) * 2048]); } } }

#define LDS_RD_B(BUF, NB)                                                     \
  { _Pragma("unroll") for (int ni = 0; ni < 2; ni++) {                        \
      _Pragma("unroll") for (int ks = 0; ks < 2; ks++) {                      \
        bfr[(NB) + ni][ks] = *(const bf16x8*)(&Bs[BUF][(rB2 ^ (ks << 6)) + ((NB) + ni) * 2048]); } } }

#define MFMA16(MB, NB)                                                        \
  { __builtin_amdgcn_s_setprio(1);                                            \
    _Pragma("unroll") for (int mi = 0; mi < 4; mi++) {                        \
      _Pragma("unroll") for (int ni = 0; ni < 2; ni++) {                      \
        _Pragma("unroll") for (int ks = 0; ks < 2; ks++) {                    \
          acc[(MB) + mi][(NB) + ni] = __builtin_amdgcn_mfma_f32_16x16x32_bf16(\
              af[mi][ks], bfr[(NB) + ni][ks], acc[(MB) + mi][(NB) + ni], 0, 0, 0); } } } \
    __builtin_amdgcn_s_setprio(0); }

#define BARB() __builtin_amdgcn_s_barrier()
#define WAITK()                                                               \
  { asm volatile("s_waitcnt lgkmcnt(0)" ::: "memory");                        \
    __builtin_amdgcn_sched_barrier(0); }

#define STAGE_A(BUF, TT, C)                                                   \
  gload_lds16(Abase + (size_t)(row0 + (C) * 64 + srow) * 2048 + (TT) * 128 + scolb, \
              &As[BUF][(C) * 8192 + tid * 16])
#define STAGE_B(BUF, TT, C)                                                   \
  gload_lds16(Bbase + (size_t)(col0 + (C) * 64 + srow) * 2048 + (TT) * 128 + scolb, \
              &Bs[BUF][(C) * 8192 + tid * 16])

#define KTILE(BUF, T_)                                                        \
  { const int Tn = (T_) + 1;                                                  \
    LDS_RD_A(BUF, 0);                                                         \
    if (Tn < NT) { STAGE_B(BUF ^ 1, Tn, 2); STAGE_B(BUF ^ 1, Tn, 3); }        \
    BARB(); WAITK(); MFMA16(0, 0); BARB();                                    \
    LDS_RD_B(BUF, 2);                                                         \
    if ((T_) + 2 < NT) { STAGE_A(BUF, (T_) + 2, 0); STAGE_A(BUF, (T_) + 2, 2); } \
    BARB(); WAITK(); MFMA16(0, 2); BARB();                                    \
    LDS_RD_A(BUF, 4);                                                         \
    if ((T_) + 2 < NT) { STAGE_B(BUF, (T_) + 2, 0); STAGE_B(BUF, (T_) + 2, 1); } \
    BARB(); WAITK(); MFMA16(4, 0); BARB();                                    \
    if ((T_) + 2 < NT) {                                                      \
      STAGE_A(BUF, (T_) + 2, 1); STAGE_A(BUF, (T_) + 2, 3);                   \
      asm volatile("s_waitcnt vmcnt(6)" ::: "memory");                        \
    } else if (Tn < NT) {                                                     \
      asm volatile("s_waitcnt vmcnt(0)" ::: "memory");                        \
    }                                                                         \
    BARB();                                                                   \
    if (Tn < NT) { LDS_RD_B(BUF ^ 1, 0); }                                    \
    MFMA16(4, 2); BARB(); }

__global__ __launch_bounds__(512, 2) void gemm_kernel(
    const __hip_bfloat16* __restrict__ A, const __hip_bfloat16* __restrict__ Bm,
    float* __restrict__ pp, float* __restrict__ diag)
{
  __shared__ __align__(16) char As[2][32768];   // [2 dbuf][256 rows][64 cols] bf16
  __shared__ __align__(16) char Bs[2][32768];

  const int tid  = threadIdx.x;
  const int lane = tid & 63;
  const int w    = tid >> 6;            // 0..7
  const int wm   = w >> 2, wn = w & 3;  // 2 x 4 wave grid

  // XCD-aware bijective swizzle: XCD x gets bm in {2x,2x+1} for all bn.
  const int fid = blockIdx.y * NBN + blockIdx.x;
  const int swz = (fid & 7) * 32 + (fid >> 3);
  const int bm = swz >> 4, bn = swz & 15;

  const long row0 = (long)bm * BM, col0 = (long)bn * BM;
  const char* Abase = (const char*)A;
  const char* Bbase = (const char*)Bm;

  const int srow  = tid >> 3;                                   // 0..63 in chunk
  const int scolb = ((tid & 7) ^ ((tid >> 3) & 7)) << 4;        // swizzled col byte

  const int dsw = (lane & 7) << 4;
  const int rA2 = (((wm * 128 + (lane & 15)) * 128) + ((lane >> 4) * 16)) ^ dsw;
  const int rB2 = (((wn * 64  + (lane & 15)) * 128) + ((lane >> 4) * 16)) ^ dsw;

  f32x4 acc[8][4] = {};
  bf16x8 af[4][2], bfr[4][2];

  // Prologue: stage tile 0 fully (8), then T1's A02, B01, A13 (6);
  // vmcnt(6) retires T0's 8; barrier; read-ahead T0's B[0..1].
  #pragma unroll
  for (int c = 0; c < 4; c++) STAGE_A(0, 0, c);
  #pragma unroll
  for (int c = 0; c < 4; c++) STAGE_B(0, 0, c);
  STAGE_A(1, 1, 0); STAGE_A(1, 1, 2);
  STAGE_B(1, 1, 0); STAGE_B(1, 1, 1);
  STAGE_A(1, 1, 1); STAGE_A(1, 1, 3);
  asm volatile("s_waitcnt vmcnt(6)" ::: "memory");
  BARB();
  LDS_RD_B(0, 0);

  #pragma unroll 1
  for (int T = 0; T < NT; T += 2) {
    KTILE(0, T);
    KTILE(1, T + 1);
  }

  // ---- Epilogue (no atomics) ----
  const bool isdiag = (bm == bn);
  const int g = lane >> 4;            // C/D: row=(lane>>4)*4+r, col=lane&15
  __syncthreads();                    // safe LDS reuse point
  float* lds_p = (float*)&As[0][0];   // [4 wn][256 rows] = 4 KB

  #pragma unroll
  for (int m = 0; m < 8; m++) {
    const int rowb = (int)row0 + wm * 128 + m * 16 + g * 4;
    float p[4] = {0.f, 0.f, 0.f, 0.f};
    #pragma unroll
    for (int n = 0; n < 4; n++) {
      const int colb = (int)col0 + wn * 64 + n * 16 + (lane & 15);
      #pragma unroll
      for (int r = 0; r < 4; r++) {
        float sim = acc[m][n][r] * TEMP_INV;
        if (isdiag && (rowb + r == colb)) diag[rowb + r] = sim;
        p[r] += __expf(sim);
      }
    }
    #pragma unroll
    for (int r = 0; r < 4; r++) {
      float s = p[r];
      s += __shfl_xor(s, 1, 64);
      s += __shfl_xor(s, 2, 64);
      s += __shfl_xor(s, 4, 64);
      s += __shfl_xor(s, 8, 64);
      if ((lane & 15) == 0)
        lds_p[wn * 256 + wm * 128 + m * 16 + g * 4 + r] = s;
    }
  }
  __syncthreads();
  if (tid < 256) {
    float s = lds_p[tid] + lds_p[256 + tid] + lds_p[512 + tid] + lds_p[768 + tid];
    pp[(size_t)bn * B_ROWS + row0 + tid] = s;   // coalesced, non-atomic
  }
}

// Kernel 3: out = mean(log(sum_bn pp[bn][i]) - diag[i])
__global__ __launch_bounds__(1024) void finalize_kernel(
    const float* __restrict__ pp, const float* __restrict__ diag,
    float* __restrict__ out)
{
  int tid = threadIdx.x;
  float acc = 0.f;
  for (int i = tid; i < B_ROWS; i += 1024) {
    float s = 0.f;
    #pragma unroll
    for (int j = 0; j < NBN; j++) s += pp[(size_t)j * B_ROWS + i];
    acc += logf(s) - diag[i];
  }
  #pragma unroll
  for (int off = 1; off < 64; off <<= 1) acc += __shfl_xor(acc, off, 64);
  __shared__ float wsum[16];
  if ((tid & 63) == 0) wsum[tid >> 6] = acc;
  __syncthreads();
  if (tid == 0) {
    float t = 0.f;
    #pragma unroll
    for (int i = 0; i < 16; i++) t += wsum[i];
    out[0] = t * (1.0f / B_ROWS);
  }
}

extern "C" void kernel_launch(void* const* d_in, const int* in_sizes, int n_in,
                              void* d_out, int out_size, void* d_ws, size_t ws_size,
                              hipStream_t stream)
{
  const float* cls = (const float*)d_in[0];
  const float* hid = (const float*)d_in[1];
  float* out = (float*)d_out;
  char* ws = (char*)d_ws;

  __hip_bfloat16* Abf = (__hip_bfloat16*)ws;                                // 8 MB
  __hip_bfloat16* Bbf = (__hip_bfloat16*)(ws + (size_t)B_ROWS * H_DIM * 2); // 8 MB
  float* pp   = (float*)(ws + (size_t)B_ROWS * H_DIM * 4);                  // 256 KB
  float* diag = pp + (size_t)NBN * B_ROWS;                                  // 16 KB

  hipLaunchKernelGGL(normalize_kernel, dim3(2 * B_ROWS / 4), dim3(256), 0, stream,
                     cls, hid, Abf, Bbf);
  hipLaunchKernelGGL(gemm_kernel, dim3(B_ROWS / BM, B_ROWS / BM), dim3(512), 0, stream,
                     Abf, Bbf, pp, diag);
  hipLaunchKernelGGL(finalize_kernel, dim3(1), dim3(1024), 0, stream,
                     pp, diag, out);
}